// Round 10
// baseline (3738.985 us; speedup 1.0000x reference)
//
#include <hip/hip_runtime.h>
#include <cstdint>
#include <cstddef>

#define B_ 4096
#define L_ 12
#define A_ 768
#define F_ 4096
#define NTRI 78

typedef __bf16 bf16x8 __attribute__((ext_vector_type(8)));
typedef float f32x4 __attribute__((ext_vector_type(4)));
typedef float f32x16 __attribute__((ext_vector_type(16)));
typedef unsigned short u16x4 __attribute__((ext_vector_type(4)));
typedef unsigned short u16x8 __attribute__((ext_vector_type(8)));

__device__ __forceinline__ unsigned short f32_to_bf16(float f) {
  unsigned int u = __float_as_uint(f);
  u += 0x7fffu + ((u >> 16) & 1u);   // round-to-nearest-even
  return (unsigned short)(u >> 16);
}

__device__ __forceinline__ void gload_lds16(const void* g, void* l) {
  __builtin_amdgcn_global_load_lds(
      (const __attribute__((address_space(1))) void*)g,
      (__attribute__((address_space(3))) void*)l,
      16, 0, 0);
}

// ---------------------------------------------------------------------------
// prep_sx: sx[l][b][a] = (x[b][l][a] - mean[l][a]) / std[l][a]  (bf16)
// ---------------------------------------------------------------------------
__global__ __launch_bounds__(256) void prep_sx(
    const float* __restrict__ x, const float* __restrict__ mean,
    const float* __restrict__ stdv, unsigned short* __restrict__ sx) {
  size_t i4 = (size_t)blockIdx.x * 256 + threadIdx.x;
  size_t e = i4 * 4;
  if (e >= (size_t)B_ * L_ * A_) return;
  unsigned int a = (unsigned int)(e % A_);
  unsigned int t = (unsigned int)(e / A_);
  unsigned int b = t / L_;
  unsigned int l = t % L_;
  float4 xv = *(const float4*)(x + e);
  float4 mv = *(const float4*)(mean + (size_t)l * A_ + a);
  float4 sv = *(const float4*)(stdv + (size_t)l * A_ + a);
  u16x4 o;
  o.x = f32_to_bf16((xv.x - mv.x) / sv.x);
  o.y = f32_to_bf16((xv.y - mv.y) / sv.y);
  o.z = f32_to_bf16((xv.z - mv.z) / sv.z);
  o.w = f32_to_bf16((xv.w - mv.w) / sv.w);
  *(u16x4*)(sx + ((size_t)l * B_ + b) * A_ + a) = o;
}

// ---------------------------------------------------------------------------
// transpose_cvt64: per z-slice (R x C f32, row-major) -> out (C x R bf16).
// ---------------------------------------------------------------------------
__global__ __launch_bounds__(256) void transpose_cvt64(
    const float* __restrict__ in, unsigned short* __restrict__ out,
    int R, int C) {
  __shared__ float tile[64][65];
  const float* inz = in + (size_t)blockIdx.z * R * C;
  unsigned short* outz = out + (size_t)blockIdx.z * R * C;
  const int c0 = blockIdx.x * 64, r0 = blockIdx.y * 64;
  const int t = threadIdx.x;
  {
    const int c = (t & 15) * 4;
    const int rb = t >> 4;
#pragma unroll
    for (int q = 0; q < 4; ++q) {
      const int r = rb + q * 16;
      float4 v = *(const float4*)(inz + (size_t)(r0 + r) * C + (c0 + c));
      tile[r][c] = v.x; tile[r][c + 1] = v.y;
      tile[r][c + 2] = v.z; tile[r][c + 3] = v.w;
    }
  }
  __syncthreads();
  {
    const int c = t >> 2;
    const int rb = (t & 3) * 16;
#pragma unroll
    for (int h = 0; h < 2; ++h) {
      u16x8 o;
#pragma unroll
      for (int j = 0; j < 8; ++j) o[j] = f32_to_bf16(tile[rb + h * 8 + j][c]);
      *(u16x8*)(outz + (size_t)(c0 + c) * R + (r0 + rb + h * 8)) = o;
    }
  }
}

// ---------------------------------------------------------------------------
// 8-wave 256x256-tile GEMM core, 32x32x16 MFMA, BK=32, ring-4 LDS,
// prefetch distance 3, counted vmcnt(8), 2 symmetric phases per K-tile
// (each: 6 ds_read_b128 + 8 MFMA), setprio clusters.
// LDS per operand: 4 slots x [256 rows][32 k] bf16 (64 B rows) = 64 KiB.
//
// Chunk swizzle s(row) = row & 3  (REVISED, round-10):
//   stored phys 16B chunk pc at (row) holds global chunk pc ^ (row & 3);
//   applied on the global source at stage time (LDS dest linear) and on
//   ds_read addrs.
// HW model (validated on r6=conflict / r7=clean / r9=conflict): wave64
// ds_read_b128 is serviced in lane groups {4k..4k+3, 32+4k..32+4k+3};
// conflict-free iff each group covers all 32 banks. With s=row&3, a group's
// rows 4k..4k+3 at k-octets {0,1} read chunk pairs {0,1},{1,0},{2,3},{3,2}
// -> even rows cover quads {0,1,2,3} of bank-half 0, odd rows of half 1:
// all 32 banks exactly once. (r9's s=(row>>1)&3 gave both even rows the
// SAME pair -> 2-way conflict, the measured 1.84e8.)
//
// Fragment mapping (32x32x16, guide m74/m101): A/B lane holds row/col
// lane&31, k-octet lane>>5; C/D: col=lane&31, row=(r&3)+8*(r>>2)+4*(lane>>5).
// Schedule per K-tile kt:
//   p1: read B ni0-1 + A mi0-3 of k-half0 ; stage A(kt+3) ; barrier ;
//       setprio(1) ; 8 MFMA ; setprio(0) ; barrier
//   p2: read B + A of k-half1 ; stage B(kt+3) ; barrier ;
//       setprio(1) ; 8 MFMA ; setprio(0) ; vmcnt(8) ; barrier
// vmcnt ledger: 4 loads/wave/tile; vmcnt(8) at p2-end publishes tile kt+1
// (kt+2,kt+3 in flight); tail drains 4 -> 0.
// Slot-reuse: slot (kt+3)&3 == (kt-1)&3; tile kt-1's reads retired before its
// closing barrier, which precedes every wave's stage issue of kt+3.
// ---------------------------------------------------------------------------
template <class KOffA, class KOffB>
__device__ __forceinline__ void gemm_core32(
    int KT, char* AS, char* BS,
    const char* gA0s, const char* gB0s,   // per-lane staging base addrs
    int ldA, int ldB,                     // global row strides in bytes
    int w, int wr, int wc, int lane,
    KOffA koffA, KOffB koffB, f32x16 (&acc)[4][2]) {
  const int l31 = lane & 31;
  const int g2 = lane >> 5;                       // k-octet within K=16
  const uint32_t swzr = (uint32_t)(l31 & 3);      // s(row) = row & 3
  const uint32_t aRow0 = (uint32_t)(wr * 128 + l31) * 64;
  const uint32_t bRow0 = (uint32_t)(wc * 64 + l31) * 64;
  const uint32_t cs0 = (((uint32_t)g2 ^ swzr) * 16);        // k-half 0
  const uint32_t cs1 = (((uint32_t)(2 + g2) ^ swzr) * 16);  // k-half 1

  auto stageA = [&](int kt) {
    const uint32_t off = koffA(kt);
    char* d = AS + (kt & 3) * 16384 + (w << 10);
    gload_lds16(gA0s + off, d);
    gload_lds16(gA0s + off + 128u * (uint32_t)ldA, d + 8192);
  };
  auto stageB = [&](int kt) {
    const uint32_t off = koffB(kt);
    char* d = BS + (kt & 3) * 16384 + (w << 10);
    gload_lds16(gB0s + off, d);
    gload_lds16(gB0s + off + 128u * (uint32_t)ldB, d + 8192);
  };

  // prologue: stage tiles 0,1,2 (12 loads); vmcnt(8) -> tile 0 landed.
  stageA(0); stageB(0);
  stageA(1); stageB(1);
  stageA(2); stageB(2);
  asm volatile("s_waitcnt vmcnt(8)" ::: "memory");
  __builtin_amdgcn_s_barrier();

  bf16x8 bk[2], ak[4];
  for (int kt = 0; kt < KT; ++kt) {
    const char* Ab = AS + (kt & 3) * 16384;
    const char* Bb = BS + (kt & 3) * 16384;
    const bool more = (kt + 3 < KT);
    // ---------------- phase 1 : k-half 0 ----------------
#pragma unroll
    for (int ni = 0; ni < 2; ++ni)
      bk[ni] = *(const bf16x8*)(Bb + bRow0 + ni * 2048 + cs0);
#pragma unroll
    for (int mi = 0; mi < 4; ++mi)
      ak[mi] = *(const bf16x8*)(Ab + aRow0 + mi * 2048 + cs0);
    if (more) stageA(kt + 3);
    asm volatile("" ::: "memory");
    __builtin_amdgcn_s_barrier();
    __builtin_amdgcn_s_setprio(1);
#pragma unroll
    for (int mi = 0; mi < 4; ++mi)
#pragma unroll
      for (int ni = 0; ni < 2; ++ni)
        acc[mi][ni] = __builtin_amdgcn_mfma_f32_32x32x16_bf16(
            ak[mi], bk[ni], acc[mi][ni], 0, 0, 0);
    __builtin_amdgcn_s_setprio(0);
    asm volatile("" ::: "memory");
    __builtin_amdgcn_s_barrier();
    // ---------------- phase 2 : k-half 1 ----------------
#pragma unroll
    for (int ni = 0; ni < 2; ++ni)
      bk[ni] = *(const bf16x8*)(Bb + bRow0 + ni * 2048 + cs1);
#pragma unroll
    for (int mi = 0; mi < 4; ++mi)
      ak[mi] = *(const bf16x8*)(Ab + aRow0 + mi * 2048 + cs1);
    if (more) stageB(kt + 3);
    asm volatile("" ::: "memory");
    __builtin_amdgcn_s_barrier();
    __builtin_amdgcn_s_setprio(1);
#pragma unroll
    for (int mi = 0; mi < 4; ++mi)
#pragma unroll
      for (int ni = 0; ni < 2; ++ni)
        acc[mi][ni] = __builtin_amdgcn_mfma_f32_32x32x16_bf16(
            ak[mi], bk[ni], acc[mi][ni], 0, 0, 0);
    __builtin_amdgcn_s_setprio(0);
    if (more)             { asm volatile("s_waitcnt vmcnt(8)" ::: "memory"); }
    else if (kt + 2 < KT) { asm volatile("s_waitcnt vmcnt(4)" ::: "memory"); }
    else if (kt + 1 < KT) { asm volatile("s_waitcnt vmcnt(0)" ::: "memory"); }
    __builtin_amdgcn_s_barrier();
  }
}

// ---------------------------------------------------------------------------
// Encoder: enc[b,l,f] = sum_a sx[l,b,a] * WencT[l,f,a]; act = JumpReLU(enc)
// grid 3072 = 12 layers x (16 m x 16 n), chunked XCD swizzle (3072 % 8 == 0)
// ---------------------------------------------------------------------------
__global__ __launch_bounds__(512, 2) void enc_gemm8(
    const unsigned short* __restrict__ sxT,   // (L,B,A)
    const unsigned short* __restrict__ wT,    // (L,F,A)
    const float* __restrict__ theta,          // (L,F)
    float* __restrict__ enc_out,              // (B,L,F)
    unsigned short* __restrict__ act)         // (L,B,F)
{
  extern __shared__ __align__(16) char lds[];
  char* AS = lds;
  char* BS = lds + 65536;
  const int b = blockIdx.x;
  const int wg = (b & 7) * 384 + (b >> 3);
  const int l = wg >> 8;
  const int blk = wg & 255;
  const int m0 = (blk & 15) * 256;
  const int n0 = (blk >> 4) * 256;
  const int tid = threadIdx.x;
  const int w = tid >> 6, lane = tid & 63;
  const int wr = w >> 2, wc = w & 3;
  // staging geometry: row = q*128 + w*16 + (lane>>2); phys chunk lane&3 holds
  // global chunk (lane&3) ^ (row&3) = (lane&3) ^ ((lane>>2)&3).
  const int srowS = w * 16 + (lane >> 2);
  const int chnkS = ((lane & 3) ^ ((lane >> 2) & 3)) * 16;

  const char* gA0s = (const char*)sxT +
      ((size_t)l * B_ + m0 + srowS) * (A_ * 2) + chnkS;
  const char* gB0s = (const char*)wT +
      ((size_t)l * F_ + n0 + srowS) * (A_ * 2) + chnkS;

  f32x16 acc[4][2] = {};
  auto koffA = [](int kt) { return (uint32_t)kt * 64u; };
  auto koffB = [](int kt) { return (uint32_t)kt * 64u; };
  gemm_core32(A_ / 32, AS, BS, gA0s, gB0s, A_ * 2, A_ * 2, w, wr, wc, lane,
              koffA, koffB, acc);

  const int l31 = lane & 31, g2 = lane >> 5;
#pragma unroll
  for (int ni = 0; ni < 2; ++ni) {
    const int gcol = n0 + wc * 64 + ni * 32 + l31;
    const float th = theta[(size_t)l * F_ + gcol];
#pragma unroll
    for (int mi = 0; mi < 4; ++mi) {
      const int rowb = m0 + wr * 128 + mi * 32 + g2 * 4;
#pragma unroll
      for (int r = 0; r < 16; ++r) {
        const float v = acc[mi][ni][r];
        const size_t grow = (size_t)(rowb + (r & 3) + 8 * (r >> 2));
        enc_out[(grow * L_ + l) * F_ + gcol] = v;
        act[((size_t)l * B_ + grow) * F_ + gcol] =
            (v > th) ? f32_to_bf16(v) : (unsigned short)0;
      }
    }
  }
}

// ---------------------------------------------------------------------------
// Decoder: logits[b,i,a] = sum_{l<=i} sum_f act[l,b,f] * WdecT[tri(i,l),a,f]
// grid 576, heavy layers first (greedy balance via dispatch order).
// ---------------------------------------------------------------------------
__global__ __launch_bounds__(512, 2) void dec_gemm8(
    const unsigned short* __restrict__ act,    // (L,B,F)
    const unsigned short* __restrict__ wdecT,  // (NTRI,A,F)
    float* __restrict__ logits)                // (B,L,A)
{
  extern __shared__ __align__(16) char lds[];
  char* AS = lds;
  char* BS = lds + 65536;
  const int b = blockIdx.x;
  const int z = b / 48;            // 0..11, heavy first
  const int blk = b - z * 48;      // 0..47
  const int i = 11 - z;
  const int m0 = (blk & 15) * 256;
  const int n0 = (blk >> 4) * 256; // {0,256,512}
  const int triBase = i * (i + 1) / 2;
  const int KT = (i + 1) * 128;    // BK=32 tiles
  const int tid = threadIdx.x;
  const int w = tid >> 6, lane = tid & 63;
  const int wr = w >> 2, wc = w & 3;
  const int srowS = w * 16 + (lane >> 2);
  const int chnkS = ((lane & 3) ^ ((lane >> 2) & 3)) * 16;

  const char* gA0s =
      (const char*)act + ((size_t)(m0 + srowS)) * (F_ * 2) + chnkS;
  const char* gB0s = (const char*)wdecT +
      ((size_t)(triBase * A_ + n0 + srowS)) * (F_ * 2) + chnkS;

  f32x16 acc[4][2] = {};
  auto koffA = [](int kt) {
    return (uint32_t)(kt >> 7) * (uint32_t)(B_ * F_ * 2) +
           (uint32_t)(kt & 127) * 64u;
  };
  auto koffB = [](int kt) {
    return (uint32_t)(kt >> 7) * (uint32_t)(A_ * F_ * 2) +
           (uint32_t)(kt & 127) * 64u;
  };
  gemm_core32(KT, AS, BS, gA0s, gB0s, F_ * 2, F_ * 2, w, wr, wc, lane,
              koffA, koffB, acc);

  const int l31 = lane & 31, g2 = lane >> 5;
#pragma unroll
  for (int mi = 0; mi < 4; ++mi) {
    const int rowb = m0 + wr * 128 + mi * 32 + g2 * 4;
#pragma unroll
    for (int ni = 0; ni < 2; ++ni) {
      const int gcol = n0 + wc * 64 + ni * 32 + l31;
#pragma unroll
      for (int r = 0; r < 16; ++r) {
        const size_t grow = (size_t)(rowb + (r & 3) + 8 * (r >> 2));
        logits[(grow * L_ + i) * A_ + gcol] = acc[mi][ni][r];
      }
    }
  }
}

// ---------------------------------------------------------------------------
extern "C" void kernel_launch(void* const* d_in, const int* in_sizes, int n_in,
                              void* d_out, int out_size, void* d_ws,
                              size_t ws_size, hipStream_t stream) {
  (void)in_sizes; (void)n_in; (void)out_size; (void)ws_size;
  const float* x = (const float*)d_in[0];
  const float* mean = (const float*)d_in[1];
  const float* stdv = (const float*)d_in[2];
  const float* Wenc = (const float*)d_in[3];
  const float* theta = (const float*)d_in[4];
  const float* Wdec = (const float*)d_in[5];

  float* logits = (float*)d_out;
  float* enc = (float*)d_out + (size_t)B_ * L_ * A_;

  char* ws = (char*)d_ws;
  const size_t actBytes = (size_t)L_ * B_ * F_ * 2;      // 402.7 MB
  const size_t sxBytes = (size_t)L_ * B_ * A_ * 2;       // 75.5 MB
  unsigned short* act = (unsigned short*)ws;
  unsigned short* sx = (unsigned short*)(ws + actBytes);
  unsigned short* wencT = (unsigned short*)(ws + actBytes + sxBytes);
  // W_dec^T only needed after the encoder; alias it over sx/wencT.
  unsigned short* wdecT = (unsigned short*)(ws + actBytes);

  hipFuncSetAttribute((const void*)enc_gemm8,
                      hipFuncAttributeMaxDynamicSharedMemorySize, 131072);
  hipFuncSetAttribute((const void*)dec_gemm8,
                      hipFuncAttributeMaxDynamicSharedMemorySize, 131072);

  prep_sx<<<(B_ * L_ * A_ / 4 + 255) / 256, 256, 0, stream>>>(x, mean, stdv, sx);
  transpose_cvt64<<<dim3(F_ / 64, A_ / 64, L_), 256, 0, stream>>>(
      Wenc, wencT, A_, F_);
  enc_gemm8<<<3072, 512, 131072, stream>>>(sx, wencT, theta, enc, act);
  transpose_cvt64<<<dim3(A_ / 64, F_ / 64, NTRI), 256, 0, stream>>>(
      Wdec, wdecT, F_, A_);
  dec_gemm8<<<576, 512, 131072, stream>>>(act, wdecT, logits);
}

// Round 11
// 2856.252 us; speedup vs baseline: 1.3091x; 1.3091x over previous
//
#include <hip/hip_runtime.h>
#include <cstdint>
#include <cstddef>

#define B_ 4096
#define L_ 12
#define A_ 768
#define F_ 4096
#define NTRI 78

typedef __bf16 bf16x8 __attribute__((ext_vector_type(8)));
typedef float f32x4 __attribute__((ext_vector_type(4)));
typedef unsigned short u16x4 __attribute__((ext_vector_type(4)));
typedef unsigned short u16x8 __attribute__((ext_vector_type(8)));

__device__ __forceinline__ unsigned short f32_to_bf16(float f) {
  unsigned int u = __float_as_uint(f);
  u += 0x7fffu + ((u >> 16) & 1u);   // round-to-nearest-even
  return (unsigned short)(u >> 16);
}

__device__ __forceinline__ void gload_lds16(const void* g, void* l) {
  __builtin_amdgcn_global_load_lds(
      (const __attribute__((address_space(1))) void*)g,
      (__attribute__((address_space(3))) void*)l,
      16, 0, 0);
}

// ---------------------------------------------------------------------------
// prep_sx: sx[l][b][a] = (x[b][l][a] - mean[l][a]) / std[l][a]  (bf16)
// ---------------------------------------------------------------------------
__global__ __launch_bounds__(256) void prep_sx(
    const float* __restrict__ x, const float* __restrict__ mean,
    const float* __restrict__ stdv, unsigned short* __restrict__ sx) {
  size_t i4 = (size_t)blockIdx.x * 256 + threadIdx.x;
  size_t e = i4 * 4;
  if (e >= (size_t)B_ * L_ * A_) return;
  unsigned int a = (unsigned int)(e % A_);
  unsigned int t = (unsigned int)(e / A_);
  unsigned int b = t / L_;
  unsigned int l = t % L_;
  float4 xv = *(const float4*)(x + e);
  float4 mv = *(const float4*)(mean + (size_t)l * A_ + a);
  float4 sv = *(const float4*)(stdv + (size_t)l * A_ + a);
  u16x4 o;
  o.x = f32_to_bf16((xv.x - mv.x) / sv.x);
  o.y = f32_to_bf16((xv.y - mv.y) / sv.y);
  o.z = f32_to_bf16((xv.z - mv.z) / sv.z);
  o.w = f32_to_bf16((xv.w - mv.w) / sv.w);
  *(u16x4*)(sx + ((size_t)l * B_ + b) * A_ + a) = o;
}

// ---------------------------------------------------------------------------
// transpose_cvt64: per z-slice (R x C f32, row-major) -> out (C x R bf16).
// ---------------------------------------------------------------------------
__global__ __launch_bounds__(256) void transpose_cvt64(
    const float* __restrict__ in, unsigned short* __restrict__ out,
    int R, int C) {
  __shared__ float tile[64][65];
  const float* inz = in + (size_t)blockIdx.z * R * C;
  unsigned short* outz = out + (size_t)blockIdx.z * R * C;
  const int c0 = blockIdx.x * 64, r0 = blockIdx.y * 64;
  const int t = threadIdx.x;
  {
    const int c = (t & 15) * 4;
    const int rb = t >> 4;
#pragma unroll
    for (int q = 0; q < 4; ++q) {
      const int r = rb + q * 16;
      float4 v = *(const float4*)(inz + (size_t)(r0 + r) * C + (c0 + c));
      tile[r][c] = v.x; tile[r][c + 1] = v.y;
      tile[r][c + 2] = v.z; tile[r][c + 3] = v.w;
    }
  }
  __syncthreads();
  {
    const int c = t >> 2;
    const int rb = (t & 3) * 16;
#pragma unroll
    for (int h = 0; h < 2; ++h) {
      u16x8 o;
#pragma unroll
      for (int j = 0; j < 8; ++j) o[j] = f32_to_bf16(tile[rb + h * 8 + j][c]);
      *(u16x8*)(outz + (size_t)(c0 + c) * R + (r0 + rb + h * 8)) = o;
    }
  }
}

// ---------------------------------------------------------------------------
// 8-wave 256x256-tile GEMM core, 16x16x32 MFMA, BK=64, ring-2 LDS with
// K-HALF staging units and COUNTED vmcnt — r6 schedule + r7-VERIFIED swizzle.
// LDS per operand: [buf:2][khalf:2][row:256][64 B] = 64 KiB (A+B = 128 KiB).
// Each khalf block is byte-for-byte an r7 BK-32 tile (0 conflicts measured):
//   store: phys chunk pc at row r holds global chunk pc ^ ((r>>1)&3)
//          (stage lane formula: chnk = (lane&3) ^ ((lane>>3)&3))
//   read:  phys chunk = g ^ ((fr>>1)&3), rows wr*128+mi*16+fr (A) etc.
// Schedule per BK-64 tile kt (4 phases, 2 barriers each, setprio on MFMA):
//   p1: read kh0 B(4)+A-lo(4) ; stage A-h0(kt+1) ; bar ; 16 MFMA ; bar
//   p2: read kh0 A-hi(4)      ; stage B-h0(kt+1) ; bar ; 16 MFMA ;
//       vmcnt(4) [kh1(kt) landed; kh0(kt+1) in flight] ; bar
//   p3: read kh1 B(4)+A-lo(4) ; stage A-h1(kt+1) ; bar ; 16 MFMA ; bar
//   p4: read kh1 A-hi(4)      ; stage B-h1(kt+1) ; bar ; 16 MFMA ;
//       vmcnt(4) [kh0(kt+1) landed; kh1(kt+1) in flight] ; bar
// vmcnt ledger (2 loads per unit, 4 units in flight = 8 loads): at p2/p4 end
// exactly 8 outstanding; vmcnt(4) waits the 4 oldest = the unit pair needed
// next phase; each staged unit gets ~3-4 phases (~600+ cyc) of latency cover.
// Drains to 0 only at the tail (kt+1==KT).
// Ring-2 safety: stage into buf^1 at p1(kt) is ordered after p4(kt-1)'s
// closing barrier, which follows every read of buf^1 (tile kt-1).
// ---------------------------------------------------------------------------
template <class KOffA, class KOffB>
__device__ __forceinline__ void gemm_core64(
    int KT, char* AS, char* BS,
    const char* gA0s, const char* gB0s,   // per-lane staging base addrs
    int ldA, int ldB,                     // global row strides in bytes
    int w, int wr, int wc, int lane,
    KOffA koffA, KOffB koffB, f32x4 (&acc)[8][4]) {
  const int g = lane >> 4;
  const int fr = lane & 15;
  const uint32_t ssr = (uint32_t)((g ^ ((fr >> 1) & 3)) * 16);
  const uint32_t aBase = (uint32_t)(wr * 128 + fr) * 64 + ssr;
  const uint32_t bBase = (uint32_t)(wc * 64 + fr) * 64 + ssr;

  auto stageA = [&](int kt, int h) {
    const uint32_t off = koffA(kt) + (uint32_t)(h * 64);
    char* d = AS + ((kt & 1) << 15) + (h << 14) + (w << 10);
    gload_lds16(gA0s + off, d);
    gload_lds16(gA0s + off + 128u * (uint32_t)ldA, d + 8192);
  };
  auto stageB = [&](int kt, int h) {
    const uint32_t off = koffB(kt) + (uint32_t)(h * 64);
    char* d = BS + ((kt & 1) << 15) + (h << 14) + (w << 10);
    gload_lds16(gB0s + off, d);
    gload_lds16(gB0s + off + 128u * (uint32_t)ldB, d + 8192);
  };

  // prologue: 4 units of tile 0 in read order; vmcnt(4) -> kh0 landed,
  // kh1 (4 loads) stays in flight — same ledger shape as steady state.
  stageA(0, 0); stageB(0, 0); stageA(0, 1); stageB(0, 1);
  asm volatile("s_waitcnt vmcnt(4)" ::: "memory");
  __builtin_amdgcn_s_barrier();

  bf16x8 bk[4], aA[4], aB[4];
  for (int kt = 0; kt < KT; ++kt) {
    const char* Ab = AS + ((kt & 1) << 15);
    const char* Bb = BS + ((kt & 1) << 15);
    const bool more = (kt + 1 < KT);
    // ---------------- phase 1: khalf0, B + A-lo ----------------
#pragma unroll
    for (int ni = 0; ni < 4; ++ni)
      bk[ni] = *(const bf16x8*)(Bb + bBase + ni * 1024);
#pragma unroll
    for (int mi = 0; mi < 4; ++mi)
      aA[mi] = *(const bf16x8*)(Ab + aBase + mi * 1024);
    if (more) stageA(kt + 1, 0);
    asm volatile("" ::: "memory");
    __builtin_amdgcn_s_barrier();
    __builtin_amdgcn_s_setprio(1);
#pragma unroll
    for (int mi = 0; mi < 4; ++mi)
#pragma unroll
      for (int ni = 0; ni < 4; ++ni)
        acc[mi][ni] = __builtin_amdgcn_mfma_f32_16x16x32_bf16(
            aA[mi], bk[ni], acc[mi][ni], 0, 0, 0);
    __builtin_amdgcn_s_setprio(0);
    asm volatile("" ::: "memory");
    __builtin_amdgcn_s_barrier();
    // ---------------- phase 2: khalf0, A-hi ----------------
#pragma unroll
    for (int mi = 0; mi < 4; ++mi)
      aB[mi] = *(const bf16x8*)(Ab + aBase + (4 + mi) * 1024);
    if (more) stageB(kt + 1, 0);
    asm volatile("" ::: "memory");
    __builtin_amdgcn_s_barrier();
    __builtin_amdgcn_s_setprio(1);
#pragma unroll
    for (int mi = 0; mi < 4; ++mi)
#pragma unroll
      for (int ni = 0; ni < 4; ++ni)
        acc[mi + 4][ni] = __builtin_amdgcn_mfma_f32_16x16x32_bf16(
            aB[mi], bk[ni], acc[mi + 4][ni], 0, 0, 0);
    __builtin_amdgcn_s_setprio(0);
    if (more) { asm volatile("s_waitcnt vmcnt(4)" ::: "memory"); }
    else      { asm volatile("s_waitcnt vmcnt(0)" ::: "memory"); }
    __builtin_amdgcn_s_barrier();
    // ---------------- phase 3: khalf1, B + A-lo ----------------
#pragma unroll
    for (int ni = 0; ni < 4; ++ni)
      bk[ni] = *(const bf16x8*)(Bb + 16384 + bBase + ni * 1024);
#pragma unroll
    for (int mi = 0; mi < 4; ++mi)
      aA[mi] = *(const bf16x8*)(Ab + 16384 + aBase + mi * 1024);
    if (more) stageA(kt + 1, 1);
    asm volatile("" ::: "memory");
    __builtin_amdgcn_s_barrier();
    __builtin_amdgcn_s_setprio(1);
#pragma unroll
    for (int mi = 0; mi < 4; ++mi)
#pragma unroll
      for (int ni = 0; ni < 4; ++ni)
        acc[mi][ni] = __builtin_amdgcn_mfma_f32_16x16x32_bf16(
            aA[mi], bk[ni], acc[mi][ni], 0, 0, 0);
    __builtin_amdgcn_s_setprio(0);
    asm volatile("" ::: "memory");
    __builtin_amdgcn_s_barrier();
    // ---------------- phase 4: khalf1, A-hi ----------------
#pragma unroll
    for (int mi = 0; mi < 4; ++mi)
      aB[mi] = *(const bf16x8*)(Ab + 16384 + aBase + (4 + mi) * 1024);
    if (more) stageB(kt + 1, 1);
    asm volatile("" ::: "memory");
    __builtin_amdgcn_s_barrier();
    __builtin_amdgcn_s_setprio(1);
#pragma unroll
    for (int mi = 0; mi < 4; ++mi)
#pragma unroll
      for (int ni = 0; ni < 4; ++ni)
        acc[mi + 4][ni] = __builtin_amdgcn_mfma_f32_16x16x32_bf16(
            aB[mi], bk[ni], acc[mi + 4][ni], 0, 0, 0);
    __builtin_amdgcn_s_setprio(0);
    if (more) { asm volatile("s_waitcnt vmcnt(4)" ::: "memory"); }
    __builtin_amdgcn_s_barrier();
  }
}

// ---------------------------------------------------------------------------
// Encoder: enc[b,l,f] = sum_a sx[l,b,a] * WencT[l,f,a]; act = JumpReLU(enc)
// grid 3072 = 12 layers x (16 m x 16 n), chunked XCD swizzle (3072 % 8 == 0)
// ---------------------------------------------------------------------------
__global__ __launch_bounds__(512, 2) void enc_gemm8(
    const unsigned short* __restrict__ sxT,   // (L,B,A)
    const unsigned short* __restrict__ wT,    // (L,F,A)
    const float* __restrict__ theta,          // (L,F)
    float* __restrict__ enc_out,              // (B,L,F)
    unsigned short* __restrict__ act)         // (L,B,F)
{
  extern __shared__ __align__(16) char lds[];
  char* AS = lds;
  char* BS = lds + 65536;
  const int b = blockIdx.x;
  const int wg = (b & 7) * 384 + (b >> 3);
  const int l = wg >> 8;
  const int blk = wg & 255;
  const int m0 = (blk & 15) * 256;
  const int n0 = (blk >> 4) * 256;
  const int tid = threadIdx.x;
  const int w = tid >> 6, lane = tid & 63;
  const int wr = w >> 2, wc = w & 3;
  // staging geometry (r7-verified): row = q*128 + w*16 + (lane>>2);
  // phys chunk lane&3 holds global chunk (lane&3) ^ ((row>>1)&3)
  //   = (lane&3) ^ ((lane>>3)&3).
  const int srowS = w * 16 + (lane >> 2);
  const int chnkS = ((lane & 3) ^ ((lane >> 3) & 3)) * 16;

  const char* gA0s = (const char*)sxT +
      ((size_t)l * B_ + m0 + srowS) * (A_ * 2) + chnkS;
  const char* gB0s = (const char*)wT +
      ((size_t)l * F_ + n0 + srowS) * (A_ * 2) + chnkS;

  f32x4 acc[8][4] = {};
  auto koffA = [](int kt) { return (uint32_t)kt * 128u; };
  auto koffB = [](int kt) { return (uint32_t)kt * 128u; };
  gemm_core64(A_ / 64, AS, BS, gA0s, gB0s, A_ * 2, A_ * 2, w, wr, wc, lane,
              koffA, koffB, acc);

  const int g = lane >> 4, fr = lane & 15;
#pragma unroll
  for (int ni = 0; ni < 4; ++ni) {
    const int gcol = n0 + wc * 64 + ni * 16 + fr;
    const float th = theta[(size_t)l * F_ + gcol];
#pragma unroll
    for (int mi = 0; mi < 8; ++mi) {
      const int growb = m0 + wr * 128 + mi * 16 + g * 4;
#pragma unroll
      for (int jj = 0; jj < 4; ++jj) {
        const float v = acc[mi][ni][jj];
        const size_t grow = (size_t)(growb + jj);
        enc_out[(grow * L_ + l) * F_ + gcol] = v;
        act[((size_t)l * B_ + grow) * F_ + gcol] =
            (v > th) ? f32_to_bf16(v) : (unsigned short)0;
      }
    }
  }
}

// ---------------------------------------------------------------------------
// Decoder: logits[b,i,a] = sum_{l<=i} sum_f act[l,b,f] * WdecT[tri(i,l),a,f]
// grid 576, heavy layers first (greedy balance via dispatch order).
// ---------------------------------------------------------------------------
__global__ __launch_bounds__(512, 2) void dec_gemm8(
    const unsigned short* __restrict__ act,    // (L,B,F)
    const unsigned short* __restrict__ wdecT,  // (NTRI,A,F)
    float* __restrict__ logits)                // (B,L,A)
{
  extern __shared__ __align__(16) char lds[];
  char* AS = lds;
  char* BS = lds + 65536;
  const int b = blockIdx.x;
  const int z = b / 48;            // 0..11, heavy first
  const int blk = b - z * 48;      // 0..47
  const int i = 11 - z;
  const int m0 = (blk & 15) * 256;
  const int n0 = (blk >> 4) * 256; // {0,256,512}
  const int triBase = i * (i + 1) / 2;
  const int KT = (i + 1) * 64;     // BK=64 tiles
  const int tid = threadIdx.x;
  const int w = tid >> 6, lane = tid & 63;
  const int wr = w >> 2, wc = w & 3;
  const int srowS = w * 16 + (lane >> 2);
  const int chnkS = ((lane & 3) ^ ((lane >> 3) & 3)) * 16;

  const char* gA0s =
      (const char*)act + ((size_t)(m0 + srowS)) * (F_ * 2) + chnkS;
  const char* gB0s = (const char*)wdecT +
      ((size_t)(triBase * A_ + n0 + srowS)) * (F_ * 2) + chnkS;

  f32x4 acc[8][4] = {};
  auto koffA = [](int kt) {
    return (uint32_t)(kt >> 6) * (uint32_t)(B_ * F_ * 2) +
           (uint32_t)(kt & 63) * 128u;
  };
  auto koffB = [](int kt) {
    return (uint32_t)(kt >> 6) * (uint32_t)(A_ * F_ * 2) +
           (uint32_t)(kt & 63) * 128u;
  };
  gemm_core64(KT, AS, BS, gA0s, gB0s, F_ * 2, F_ * 2, w, wr, wc, lane,
              koffA, koffB, acc);

  const int g = lane >> 4, fr = lane & 15;
#pragma unroll
  for (int mi = 0; mi < 8; ++mi) {
    const int growb = m0 + wr * 128 + mi * 16 + g * 4;
#pragma unroll
    for (int ni = 0; ni < 4; ++ni) {
      const int gcol = n0 + wc * 64 + ni * 16 + fr;
#pragma unroll
      for (int jj = 0; jj < 4; ++jj)
        logits[((size_t)(growb + jj) * L_ + i) * A_ + gcol] = acc[mi][ni][jj];
    }
  }
}

// ---------------------------------------------------------------------------
extern "C" void kernel_launch(void* const* d_in, const int* in_sizes, int n_in,
                              void* d_out, int out_size, void* d_ws,
                              size_t ws_size, hipStream_t stream) {
  (void)in_sizes; (void)n_in; (void)out_size; (void)ws_size;
  const float* x = (const float*)d_in[0];
  const float* mean = (const float*)d_in[1];
  const float* stdv = (const float*)d_in[2];
  const float* Wenc = (const float*)d_in[3];
  const float* theta = (const float*)d_in[4];
  const float* Wdec = (const float*)d_in[5];

  float* logits = (float*)d_out;
  float* enc = (float*)d_out + (size_t)B_ * L_ * A_;

  char* ws = (char*)d_ws;
  const size_t actBytes = (size_t)L_ * B_ * F_ * 2;      // 402.7 MB
  const size_t sxBytes = (size_t)L_ * B_ * A_ * 2;       // 75.5 MB
  unsigned short* act = (unsigned short*)ws;
  unsigned short* sx = (unsigned short*)(ws + actBytes);
  unsigned short* wencT = (unsigned short*)(ws + actBytes + sxBytes);
  // W_dec^T only needed after the encoder; alias it over sx/wencT.
  unsigned short* wdecT = (unsigned short*)(ws + actBytes);

  hipFuncSetAttribute((const void*)enc_gemm8,
                      hipFuncAttributeMaxDynamicSharedMemorySize, 131072);
  hipFuncSetAttribute((const void*)dec_gemm8,
                      hipFuncAttributeMaxDynamicSharedMemorySize, 131072);

  prep_sx<<<(B_ * L_ * A_ / 4 + 255) / 256, 256, 0, stream>>>(x, mean, stdv, sx);
  transpose_cvt64<<<dim3(F_ / 64, A_ / 64, L_), 256, 0, stream>>>(
      Wenc, wencT, A_, F_);
  enc_gemm8<<<3072, 512, 131072, stream>>>(sx, wencT, theta, enc, act);
  transpose_cvt64<<<dim3(A_ / 64, F_ / 64, NTRI), 256, 0, stream>>>(
      Wdec, wdecT, F_, A_);
  dec_gemm8<<<576, 512, 131072, stream>>>(act, wdecT, logits);
}

// Round 12
// 2756.624 us; speedup vs baseline: 1.3564x; 1.0361x over previous
//
#include <hip/hip_runtime.h>
#include <cstdint>
#include <cstddef>

#define B_ 4096
#define L_ 12
#define A_ 768
#define F_ 4096
#define NTRI 78

typedef __bf16 bf16x8 __attribute__((ext_vector_type(8)));
typedef float f32x4 __attribute__((ext_vector_type(4)));
typedef unsigned short u16x4 __attribute__((ext_vector_type(4)));
typedef unsigned short u16x8 __attribute__((ext_vector_type(8)));

__device__ __forceinline__ unsigned short f32_to_bf16(float f) {
  unsigned int u = __float_as_uint(f);
  u += 0x7fffu + ((u >> 16) & 1u);   // round-to-nearest-even
  return (unsigned short)(u >> 16);
}

__device__ __forceinline__ void gload_lds16(const void* g, void* l) {
  __builtin_amdgcn_global_load_lds(
      (const __attribute__((address_space(1))) void*)g,
      (__attribute__((address_space(3))) void*)l,
      16, 0, 0);
}

// ---------------------------------------------------------------------------
// prep_sx: sx[l][b][a] = (x[b][l][a] - mean[l][a]) / std[l][a]  (bf16)
// ---------------------------------------------------------------------------
__global__ __launch_bounds__(256) void prep_sx(
    const float* __restrict__ x, const float* __restrict__ mean,
    const float* __restrict__ stdv, unsigned short* __restrict__ sx) {
  size_t i4 = (size_t)blockIdx.x * 256 + threadIdx.x;
  size_t e = i4 * 4;
  if (e >= (size_t)B_ * L_ * A_) return;
  unsigned int a = (unsigned int)(e % A_);
  unsigned int t = (unsigned int)(e / A_);
  unsigned int b = t / L_;
  unsigned int l = t % L_;
  float4 xv = *(const float4*)(x + e);
  float4 mv = *(const float4*)(mean + (size_t)l * A_ + a);
  float4 sv = *(const float4*)(stdv + (size_t)l * A_ + a);
  u16x4 o;
  o.x = f32_to_bf16((xv.x - mv.x) / sv.x);
  o.y = f32_to_bf16((xv.y - mv.y) / sv.y);
  o.z = f32_to_bf16((xv.z - mv.z) / sv.z);
  o.w = f32_to_bf16((xv.w - mv.w) / sv.w);
  *(u16x4*)(sx + ((size_t)l * B_ + b) * A_ + a) = o;
}

// ---------------------------------------------------------------------------
// transpose_cvt64: per z-slice (R x C f32, row-major) -> out (C x R bf16).
// ---------------------------------------------------------------------------
__global__ __launch_bounds__(256) void transpose_cvt64(
    const float* __restrict__ in, unsigned short* __restrict__ out,
    int R, int C) {
  __shared__ float tile[64][65];
  const float* inz = in + (size_t)blockIdx.z * R * C;
  unsigned short* outz = out + (size_t)blockIdx.z * R * C;
  const int c0 = blockIdx.x * 64, r0 = blockIdx.y * 64;
  const int t = threadIdx.x;
  {
    const int c = (t & 15) * 4;
    const int rb = t >> 4;
#pragma unroll
    for (int q = 0; q < 4; ++q) {
      const int r = rb + q * 16;
      float4 v = *(const float4*)(inz + (size_t)(r0 + r) * C + (c0 + c));
      tile[r][c] = v.x; tile[r][c + 1] = v.y;
      tile[r][c + 2] = v.z; tile[r][c + 3] = v.w;
    }
  }
  __syncthreads();
  {
    const int c = t >> 2;
    const int rb = (t & 3) * 16;
#pragma unroll
    for (int h = 0; h < 2; ++h) {
      u16x8 o;
#pragma unroll
      for (int j = 0; j < 8; ++j) o[j] = f32_to_bf16(tile[rb + h * 8 + j][c]);
      *(u16x8*)(outz + (size_t)(c0 + c) * R + (r0 + rb + h * 8)) = o;
    }
  }
}

// ---------------------------------------------------------------------------
// 8-wave 256x256-tile GEMM core (r11, UNCHANGED): 16x16x32 MFMA, BK=64,
// ring-2 LDS with k-half staging units, counted vmcnt(4), 4 phases/K-tile,
// setprio clusters, r7-verified 0-conflict chunk swizzle.
// ---------------------------------------------------------------------------
template <class KOffA, class KOffB>
__device__ __forceinline__ void gemm_core64(
    int KT, char* AS, char* BS,
    const char* gA0s, const char* gB0s,   // per-lane staging base addrs
    int ldA, int ldB,                     // global row strides in bytes
    int w, int wr, int wc, int lane,
    KOffA koffA, KOffB koffB, f32x4 (&acc)[8][4]) {
  const int g = lane >> 4;
  const int fr = lane & 15;
  const uint32_t ssr = (uint32_t)((g ^ ((fr >> 1) & 3)) * 16);
  const uint32_t aBase = (uint32_t)(wr * 128 + fr) * 64 + ssr;
  const uint32_t bBase = (uint32_t)(wc * 64 + fr) * 64 + ssr;

  auto stageA = [&](int kt, int h) {
    const uint32_t off = koffA(kt) + (uint32_t)(h * 64);
    char* d = AS + ((kt & 1) << 15) + (h << 14) + (w << 10);
    gload_lds16(gA0s + off, d);
    gload_lds16(gA0s + off + 128u * (uint32_t)ldA, d + 8192);
  };
  auto stageB = [&](int kt, int h) {
    const uint32_t off = koffB(kt) + (uint32_t)(h * 64);
    char* d = BS + ((kt & 1) << 15) + (h << 14) + (w << 10);
    gload_lds16(gB0s + off, d);
    gload_lds16(gB0s + off + 128u * (uint32_t)ldB, d + 8192);
  };

  stageA(0, 0); stageB(0, 0); stageA(0, 1); stageB(0, 1);
  asm volatile("s_waitcnt vmcnt(4)" ::: "memory");
  __builtin_amdgcn_s_barrier();

  bf16x8 bk[4], aA[4], aB[4];
  for (int kt = 0; kt < KT; ++kt) {
    const char* Ab = AS + ((kt & 1) << 15);
    const char* Bb = BS + ((kt & 1) << 15);
    const bool more = (kt + 1 < KT);
    // ---------------- phase 1: khalf0, B + A-lo ----------------
#pragma unroll
    for (int ni = 0; ni < 4; ++ni)
      bk[ni] = *(const bf16x8*)(Bb + bBase + ni * 1024);
#pragma unroll
    for (int mi = 0; mi < 4; ++mi)
      aA[mi] = *(const bf16x8*)(Ab + aBase + mi * 1024);
    if (more) stageA(kt + 1, 0);
    asm volatile("" ::: "memory");
    __builtin_amdgcn_s_barrier();
    __builtin_amdgcn_s_setprio(1);
#pragma unroll
    for (int mi = 0; mi < 4; ++mi)
#pragma unroll
      for (int ni = 0; ni < 4; ++ni)
        acc[mi][ni] = __builtin_amdgcn_mfma_f32_16x16x32_bf16(
            aA[mi], bk[ni], acc[mi][ni], 0, 0, 0);
    __builtin_amdgcn_s_setprio(0);
    asm volatile("" ::: "memory");
    __builtin_amdgcn_s_barrier();
    // ---------------- phase 2: khalf0, A-hi ----------------
#pragma unroll
    for (int mi = 0; mi < 4; ++mi)
      aB[mi] = *(const bf16x8*)(Ab + aBase + (4 + mi) * 1024);
    if (more) stageB(kt + 1, 0);
    asm volatile("" ::: "memory");
    __builtin_amdgcn_s_barrier();
    __builtin_amdgcn_s_setprio(1);
#pragma unroll
    for (int mi = 0; mi < 4; ++mi)
#pragma unroll
      for (int ni = 0; ni < 4; ++ni)
        acc[mi + 4][ni] = __builtin_amdgcn_mfma_f32_16x16x32_bf16(
            aB[mi], bk[ni], acc[mi + 4][ni], 0, 0, 0);
    __builtin_amdgcn_s_setprio(0);
    if (more) { asm volatile("s_waitcnt vmcnt(4)" ::: "memory"); }
    else      { asm volatile("s_waitcnt vmcnt(0)" ::: "memory"); }
    __builtin_amdgcn_s_barrier();
    // ---------------- phase 3: khalf1, B + A-lo ----------------
#pragma unroll
    for (int ni = 0; ni < 4; ++ni)
      bk[ni] = *(const bf16x8*)(Bb + 16384 + bBase + ni * 1024);
#pragma unroll
    for (int mi = 0; mi < 4; ++mi)
      aA[mi] = *(const bf16x8*)(Ab + 16384 + aBase + mi * 1024);
    if (more) stageA(kt + 1, 1);
    asm volatile("" ::: "memory");
    __builtin_amdgcn_s_barrier();
    __builtin_amdgcn_s_setprio(1);
#pragma unroll
    for (int mi = 0; mi < 4; ++mi)
#pragma unroll
      for (int ni = 0; ni < 4; ++ni)
        acc[mi][ni] = __builtin_amdgcn_mfma_f32_16x16x32_bf16(
            aA[mi], bk[ni], acc[mi][ni], 0, 0, 0);
    __builtin_amdgcn_s_setprio(0);
    asm volatile("" ::: "memory");
    __builtin_amdgcn_s_barrier();
    // ---------------- phase 4: khalf1, A-hi ----------------
#pragma unroll
    for (int mi = 0; mi < 4; ++mi)
      aB[mi] = *(const bf16x8*)(Ab + 16384 + aBase + (4 + mi) * 1024);
    if (more) stageB(kt + 1, 1);
    asm volatile("" ::: "memory");
    __builtin_amdgcn_s_barrier();
    __builtin_amdgcn_s_setprio(1);
#pragma unroll
    for (int mi = 0; mi < 4; ++mi)
#pragma unroll
      for (int ni = 0; ni < 4; ++ni)
        acc[mi + 4][ni] = __builtin_amdgcn_mfma_f32_16x16x32_bf16(
            aB[mi], bk[ni], acc[mi + 4][ni], 0, 0, 0);
    __builtin_amdgcn_s_setprio(0);
    if (more) { asm volatile("s_waitcnt vmcnt(4)" ::: "memory"); }
    __builtin_amdgcn_s_barrier();
  }
}

// ---------------------------------------------------------------------------
// Fused encoder + partial Wdec transpose. grid 6528 = 17*384:
//   b%17 <  8 -> enc role (3072 blocks, XCD-swizzled 256x256 enc GEMM)
//   b%17 >= 8 -> transpose role (3456 blocks): tri z in [24,78), one (y,z)
//               column strip of 12 64x64 tiles each.
// Alias safety: wdecT[z] for z>=24 starts at byte z*6291456 >= 150994944 =
// exactly the end of sx+wencT -> transpose writes never touch enc's inputs.
// Roles touch disjoint buffers; barriers are block-uniform per role.
// ---------------------------------------------------------------------------
__global__ __launch_bounds__(512, 2) void enc_fused(
    const unsigned short* __restrict__ sxT,   // (L,B,A)
    const unsigned short* __restrict__ wT,    // (L,F,A)
    const float* __restrict__ theta,          // (L,F)
    float* __restrict__ enc_out,              // (B,L,F)
    unsigned short* __restrict__ act,         // (L,B,F)
    const float* __restrict__ wdec_in,        // (NTRI,F,A) f32
    unsigned short* __restrict__ wdecT_out)   // (NTRI,A,F) bf16
{
  extern __shared__ __align__(16) char lds[];
  const int bidx = blockIdx.x;
  const int grp = bidx / 17;
  const int rem = bidx - grp * 17;

  if (rem >= 8) {
    // ---------------- Wdec transpose role ----------------
    const int tr = grp * 9 + (rem - 8);     // 0..3455
    const int y = tr & 63;
    const int z = 24 + (tr >> 6);           // 24..77
    float (*tile)[65] = (float(*)[65])lds;
    const float* inz = wdec_in + (size_t)z * F_ * A_;
    unsigned short* outz = wdecT_out + (size_t)z * F_ * A_;
    const int r0 = y * 64;                  // F-dim tile base
    const int t = threadIdx.x;
    for (int xq = 0; xq < 12; ++xq) {
      const int c0 = xq * 64;               // A-dim tile base
      {
        const int c = (t & 15) * 4;
        const int rb = t >> 4;              // 0..31
#pragma unroll
        for (int q = 0; q < 2; ++q) {
          const int r = rb + q * 32;
          float4 v = *(const float4*)(inz + (size_t)(r0 + r) * A_ + (c0 + c));
          tile[r][c] = v.x; tile[r][c + 1] = v.y;
          tile[r][c + 2] = v.z; tile[r][c + 3] = v.w;
        }
      }
      __syncthreads();
      {
        const int c = t >> 3;               // 0..63
        const int rb8 = (t & 7) * 8;
        u16x8 o;
#pragma unroll
        for (int j = 0; j < 8; ++j) o[j] = f32_to_bf16(tile[rb8 + j][c]);
        *(u16x8*)(outz + (size_t)(c0 + c) * F_ + (r0 + rb8)) = o;
      }
      __syncthreads();
    }
    return;
  }

  // ---------------- encoder GEMM role (r11 body) ----------------
  char* AS = lds;
  char* BS = lds + 65536;
  const int e = grp * 8 + rem;              // 0..3071
  const int wg = (e & 7) * 384 + (e >> 3);  // bijective XCD chunk swizzle
  const int l = wg >> 8;
  const int blk = wg & 255;
  const int m0 = (blk & 15) * 256;
  const int n0 = (blk >> 4) * 256;
  const int tid = threadIdx.x;
  const int w = tid >> 6, lane = tid & 63;
  const int wr = w >> 2, wc = w & 3;
  const int srowS = w * 16 + (lane >> 2);
  const int chnkS = ((lane & 3) ^ ((lane >> 3) & 3)) * 16;

  const char* gA0s = (const char*)sxT +
      ((size_t)l * B_ + m0 + srowS) * (A_ * 2) + chnkS;
  const char* gB0s = (const char*)wT +
      ((size_t)l * F_ + n0 + srowS) * (A_ * 2) + chnkS;

  f32x4 acc[8][4] = {};
  auto koffA = [](int kt) { return (uint32_t)kt * 128u; };
  auto koffB = [](int kt) { return (uint32_t)kt * 128u; };
  gemm_core64(A_ / 64, AS, BS, gA0s, gB0s, A_ * 2, A_ * 2, w, wr, wc, lane,
              koffA, koffB, acc);

  const int g = lane >> 4, fr = lane & 15;
#pragma unroll
  for (int ni = 0; ni < 4; ++ni) {
    const int gcol = n0 + wc * 64 + ni * 16 + fr;
    const float th = theta[(size_t)l * F_ + gcol];
#pragma unroll
    for (int mi = 0; mi < 8; ++mi) {
      const int growb = m0 + wr * 128 + mi * 16 + g * 4;
#pragma unroll
      for (int jj = 0; jj < 4; ++jj) {
        const float v = acc[mi][ni][jj];
        const size_t grow = (size_t)(growb + jj);
        enc_out[(grow * L_ + l) * F_ + gcol] = v;
        act[((size_t)l * B_ + grow) * F_ + gcol] =
            (v > th) ? f32_to_bf16(v) : (unsigned short)0;
      }
    }
  }
}

// ---------------------------------------------------------------------------
// Decoder (r11, UNCHANGED): grid 576, heavy layers first.
// ---------------------------------------------------------------------------
__global__ __launch_bounds__(512, 2) void dec_gemm8(
    const unsigned short* __restrict__ act,    // (L,B,F)
    const unsigned short* __restrict__ wdecT,  // (NTRI,A,F)
    float* __restrict__ logits)                // (B,L,A)
{
  extern __shared__ __align__(16) char lds[];
  char* AS = lds;
  char* BS = lds + 65536;
  const int b = blockIdx.x;
  const int z = b / 48;            // 0..11, heavy first
  const int blk = b - z * 48;      // 0..47
  const int i = 11 - z;
  const int m0 = (blk & 15) * 256;
  const int n0 = (blk >> 4) * 256; // {0,256,512}
  const int triBase = i * (i + 1) / 2;
  const int KT = (i + 1) * 64;     // BK=64 tiles
  const int tid = threadIdx.x;
  const int w = tid >> 6, lane = tid & 63;
  const int wr = w >> 2, wc = w & 3;
  const int srowS = w * 16 + (lane >> 2);
  const int chnkS = ((lane & 3) ^ ((lane >> 3) & 3)) * 16;

  const char* gA0s =
      (const char*)act + ((size_t)(m0 + srowS)) * (F_ * 2) + chnkS;
  const char* gB0s = (const char*)wdecT +
      ((size_t)(triBase * A_ + n0 + srowS)) * (F_ * 2) + chnkS;

  f32x4 acc[8][4] = {};
  auto koffA = [](int kt) {
    return (uint32_t)(kt >> 6) * (uint32_t)(B_ * F_ * 2) +
           (uint32_t)(kt & 63) * 128u;
  };
  auto koffB = [](int kt) {
    return (uint32_t)(kt >> 6) * (uint32_t)(A_ * F_ * 2) +
           (uint32_t)(kt & 63) * 128u;
  };
  gemm_core64(KT, AS, BS, gA0s, gB0s, F_ * 2, F_ * 2, w, wr, wc, lane,
              koffA, koffB, acc);

  const int g = lane >> 4, fr = lane & 15;
#pragma unroll
  for (int mi = 0; mi < 8; ++mi) {
    const int growb = m0 + wr * 128 + mi * 16 + g * 4;
#pragma unroll
    for (int ni = 0; ni < 4; ++ni) {
      const int gcol = n0 + wc * 64 + ni * 16 + fr;
#pragma unroll
      for (int jj = 0; jj < 4; ++jj)
        logits[((size_t)(growb + jj) * L_ + i) * A_ + gcol] = acc[mi][ni][jj];
    }
  }
}

// ---------------------------------------------------------------------------
extern "C" void kernel_launch(void* const* d_in, const int* in_sizes, int n_in,
                              void* d_out, int out_size, void* d_ws,
                              size_t ws_size, hipStream_t stream) {
  (void)in_sizes; (void)n_in; (void)out_size; (void)ws_size;
  const float* x = (const float*)d_in[0];
  const float* mean = (const float*)d_in[1];
  const float* stdv = (const float*)d_in[2];
  const float* Wenc = (const float*)d_in[3];
  const float* theta = (const float*)d_in[4];
  const float* Wdec = (const float*)d_in[5];

  float* logits = (float*)d_out;
  float* enc = (float*)d_out + (size_t)B_ * L_ * A_;

  char* ws = (char*)d_ws;
  const size_t actBytes = (size_t)L_ * B_ * F_ * 2;      // 402.7 MB
  const size_t sxBytes = (size_t)L_ * B_ * A_ * 2;       // 75.5 MB
  unsigned short* act = (unsigned short*)ws;
  unsigned short* sx = (unsigned short*)(ws + actBytes);
  unsigned short* wencT = (unsigned short*)(ws + actBytes + sxBytes);
  // wdecT aliases over sx+wencT; tris >=24 lie beyond them (safe during enc).
  unsigned short* wdecT = (unsigned short*)(ws + actBytes);

  hipFuncSetAttribute((const void*)enc_fused,
                      hipFuncAttributeMaxDynamicSharedMemorySize, 131072);
  hipFuncSetAttribute((const void*)dec_gemm8,
                      hipFuncAttributeMaxDynamicSharedMemorySize, 131072);

  prep_sx<<<(B_ * L_ * A_ / 4 + 255) / 256, 256, 0, stream>>>(x, mean, stdv, sx);
  transpose_cvt64<<<dim3(F_ / 64, A_ / 64, L_), 256, 0, stream>>>(
      Wenc, wencT, A_, F_);
  // enc GEMM + Wdec transpose (tris 24..77) co-scheduled:
  enc_fused<<<6528, 512, 131072, stream>>>(sx, wencT, theta, enc, act,
                                           Wdec, wdecT);
  // remaining Wdec tris 0..23 (their destination aliases sx/wencT, which are
  // dead once enc_fused completes):
  transpose_cvt64<<<dim3(A_ / 64, F_ / 64, 24), 256, 0, stream>>>(
      Wdec, wdecT, F_, A_);
  dec_gemm8<<<576, 512, 131072, stream>>>(act, wdecT, logits);
}